// Round 14
// baseline (296.977 us; speedup 1.0000x reference)
//
#include <hip/hip_runtime.h>

#define N 8192
#define D 256
#define BM 128                    // I-tile rows (per task)
#define BJ 64                     // J-tile rows (per jj step)
#define JG 8                      // J-tiles per task
#define GJ (N / BJ / JG)          // 16
#define GI (N / BM)               // 64
#define NBLOCK 768                // 16 waves each; 768*16 = 3*GI*GJ*4 tasks

typedef int   i32x8 __attribute__((ext_vector_type(8)));
typedef float f32x4 __attribute__((ext_vector_type(4)));
typedef float f32x2 __attribute__((ext_vector_type(2)));

// -------- prep: fp32 -> fp8 e4m3 (packed), norms of the DEQUANTIZED values ----
__device__ __forceinline__ unsigned pack_fp8x4(float a, float b, float c, float d) {
    unsigned lo = __builtin_amdgcn_cvt_pk_fp8_f32(a, b, 0, false);
    return __builtin_amdgcn_cvt_pk_fp8_f32(c, d, lo, true);
}
__device__ __forceinline__ float dequant_sumsq(unsigned q) {
    const float v0 = __builtin_amdgcn_cvt_f32_fp8(q, 0);
    const float v1 = __builtin_amdgcn_cvt_f32_fp8(q, 1);
    const float v2 = __builtin_amdgcn_cvt_f32_fp8(q, 2);
    const float v3 = __builtin_amdgcn_cvt_f32_fp8(q, 3);
    return fmaf(v0, v0, fmaf(v1, v1, fmaf(v2, v2, v3 * v3)));
}

__global__ void prep_kernel(const float* __restrict__ x1, const float* __restrict__ x2,
                            unsigned* __restrict__ x1q, unsigned* __restrict__ x2q,
                            unsigned* __restrict__ pq,
                            float* __restrict__ sq1, float* __restrict__ sq2,
                            float* __restrict__ sqp) {
    const int tid = threadIdx.x, lane = tid & 63, wv = tid >> 6;
    const int row = blockIdx.x * 4 + wv;
    const size_t eb = (size_t)row * D + lane * 4;
    const float4 a = *(const float4*)(x1 + eb);
    const float4 b = *(const float4*)(x2 + eb);
    const float px = 0.5f * (a.x + b.x), py = 0.5f * (a.y + b.y);
    const float pz = 0.5f * (a.z + b.z), pw = 0.5f * (a.w + b.w);
    const unsigned qa = pack_fp8x4(a.x, a.y, a.z, a.w);
    const unsigned qb = pack_fp8x4(b.x, b.y, b.z, b.w);
    const unsigned qp = pack_fp8x4(px, py, pz, pw);
    const size_t wb = (size_t)row * (D / 4) + lane;
    x1q[wb] = qa; x2q[wb] = qb; pq[wb] = qp;
    float s1 = dequant_sumsq(qa), s2 = dequant_sumsq(qb), sp = dequant_sumsq(qp);
    #pragma unroll
    for (int o = 32; o > 0; o >>= 1) {
        s1 += __shfl_down(s1, o, 64);
        s2 += __shfl_down(s2, o, 64);
        sp += __shfl_down(sp, o, 64);
    }
    if (lane == 0) { sq1[row] = s1; sq2[row] = s2; sqp[row] = sp; }
}

// -------- main ---------------------------------------------------------------
__device__ __forceinline__ f32x4 mfma8(i32x8 a, i32x8 b, f32x4 c) {
    return __builtin_amdgcn_mfma_scale_f32_16x16x128_f8f6f4(
        a, b, c, 0, 0, 0, 0x7F7F7F7F, 0, 0x7F7F7F7F);
}

__device__ __forceinline__ float logsumP(const f32x4 (&acc)[4][2],
                                         const f32x2 (&sa01)[4], const f32x2 (&sa23)[4],
                                         const float sb[2]) {
    float s = 0.0f;
    #pragma unroll
    for (int ti = 0; ti < 4; ++ti) {
        f32x2 pr = {1.0f, 1.0f};
        #pragma unroll
        for (int tj = 0; tj < 2; ++tj) {
            const f32x2 sbv = {sb[tj], sb[tj]};
            const f32x2 t01 = sa01[ti] + sbv, t23 = sa23[ti] + sbv;
            const f32x2 v01 = {acc[ti][tj][0], acc[ti][tj][1]};
            const f32x2 v23 = {acc[ti][tj][2], acc[ti][tj][3]};
            f32x2 d01 = t01 - 2.0f * v01;
            f32x2 d23 = t23 - 2.0f * v23;
            d01 = __builtin_elementwise_max(d01, (f32x2){1.0f, 1.0f});
            d23 = __builtin_elementwise_max(d23, (f32x2){1.0f, 1.0f});
            pr *= d01; pr *= d23;
        }
        s += __logf(pr.x * pr.y);   // product of 8 dists <= (1.5e3)^8, fp32-safe
    }
    return s;
}

__device__ __forceinline__ float logsumStraddle(const f32x4 (&acc)[4][2],
                                                const f32x2 (&sa01)[4], const f32x2 (&sa23)[4],
                                                const float sb[2],
                                                int wr, int wc, int quad, int l15,
                                                int I0, int J0) {
    float s = 0.0f;
    #pragma unroll
    for (int ti = 0; ti < 4; ++ti) {
        #pragma unroll
        for (int tj = 0; tj < 2; ++tj) {
            const int j = J0 + wc * 32 + tj * 16 + l15;
            float pr = 1.0f;
            #pragma unroll
            for (int r = 0; r < 4; ++r) {
                const int i = I0 + wr * 64 + ti * 16 + quad * 4 + r;
                const float sav = (r < 2) ? ((r & 1) ? sa01[ti].y : sa01[ti].x)
                                          : ((r & 1) ? sa23[ti].y : sa23[ti].x);
                float d = fmaf(-2.0f, acc[ti][tj][r], sav + sb[tj]);
                d = fmaxf(d, 1.0f);
                const float t = (j > i) ? d : 1.0f;
                const float u = (j >= i) ? d : 1.0f;
                pr *= t * u;
            }
            s += __logf(pr);
        }
    }
    return s;
}

// 1024 threads = 16 independent wave-tasks; no barriers until final reduce.
__global__ __launch_bounds__(1024) void mqjs_main(
    const unsigned char* __restrict__ x1q, const unsigned char* __restrict__ x2q,
    const unsigned char* __restrict__ pq,
    const float* __restrict__ sq1, const float* __restrict__ sq2,
    const float* __restrict__ sqp, float* __restrict__ partials) {

    __shared__ float red[16];

    const int tid = threadIdx.x;
    const int lane = tid & 63;
    const int wv = tid >> 6;                  // 0..15
    const int quad = lane >> 4, l15 = lane & 15;

    // stride task mapping: block's 16 tasks spread across z/by for balance
    const int task = wv * NBLOCK + blockIdx.x;          // 0..12287
    const int ob = task >> 2, owv = task & 3;
    const int z = ob / (GI * GJ);
    const int rem = ob - z * (GI * GJ);
    const int by = rem / GJ, bx = rem - by * GJ;
    const int wr = owv >> 1, wc = owv & 1;    // 64 I-rows x 32 J-cols slice

    const int I0 = by * BM;
    const int jbase = bx * JG;
    const float wse = -(float)N / (float)(N - 1);

    int jj0 = 0;
    if (z == 2) {                              // first J-tile touching j >= i
        jj0 = 2 * by - jbase;
        if (jj0 < 0) jj0 = 0;
    }

    float tsum = 0.0f;

    if (jj0 < JG) {
        const unsigned char* Ag = (z == 1) ? x2q : x1q;
        const unsigned char* Bg = (z == 2) ? x1q : pq;
        const float* sqAg = (z == 1) ? sq2 : sq1;
        const float* sqBg = (z == 2) ? sq1 : sqp;

        // A fragments + sqA from global (once per task; L2-resident)
        i32x8 af[2][4];
        f32x2 sa01[4], sa23[4];
        #pragma unroll
        for (int ti = 0; ti < 4; ++ti) {
            #pragma unroll
            for (int kc = 0; kc < 2; ++kc) {
                const size_t ro = (size_t)(I0 + wr * 64 + ti * 16 + l15) * D + kc * 128 + quad * 32;
                af[kc][ti] = *(const i32x8*)(Ag + ro);
            }
            const int sbase = I0 + wr * 64 + ti * 16 + quad * 4;
            sa01[ti] = (f32x2){sqAg[sbase], sqAg[sbase + 1]};
            sa23[ti] = (f32x2){sqAg[sbase + 2], sqAg[sbase + 3]};
        }

        for (int jj = jj0; jj < JG; ++jj) {
            const int J0 = (jbase + jj) * BJ;

            i32x8 bfr[2][2];                   // direct global loads (L2/LLC-hot)
            #pragma unroll
            for (int kc = 0; kc < 2; ++kc)
                #pragma unroll
                for (int tj = 0; tj < 2; ++tj)
                    bfr[kc][tj] = *(const i32x8*)(Bg +
                        (size_t)(J0 + wc * 32 + tj * 16 + l15) * D + kc * 128 + quad * 32);

            float sb[2];
            #pragma unroll
            for (int tj = 0; tj < 2; ++tj) sb[tj] = sqBg[J0 + wc * 32 + tj * 16 + l15];

            f32x4 acc[4][2];
            #pragma unroll
            for (int a = 0; a < 4; ++a)
                #pragma unroll
                for (int b = 0; b < 2; ++b)
                    acc[a][b] = (f32x4){0.f, 0.f, 0.f, 0.f};
            #pragma unroll
            for (int kc = 0; kc < 2; ++kc)
                #pragma unroll
                for (int ti = 0; ti < 4; ++ti)
                    #pragma unroll
                    for (int tj = 0; tj < 2; ++tj)
                        acc[ti][tj] = mfma8(af[kc][ti], bfr[kc][tj], acc[ti][tj]);

            if (z < 2) {
                tsum += 0.5f * logsumP(acc, sa01, sa23, sb);
            } else if (J0 >= I0 + BM) {
                tsum += wse * logsumP(acc, sa01, sa23, sb);      // upper full: 2 * 0.5 * wse
            } else {
                tsum += 0.5f * wse * logsumStraddle(acc, sa01, sa23, sb, wr, wc, quad, l15, I0, J0);
            }
        }
    }

    #pragma unroll
    for (int o = 32; o > 0; o >>= 1) tsum += __shfl_down(tsum, o, 64);
    if (lane == 0) red[wv] = tsum;
    __syncthreads();
    if (tid == 0) {
        float s = 0.0f;
        #pragma unroll
        for (int i = 0; i < 16; ++i) s += red[i];
        partials[blockIdx.x] = s;
    }
}

// reduce 768 partials (double accumulation) -> final scalar
__global__ void finalize_kernel(const float* __restrict__ partials, float* __restrict__ out) {
    const int tid = threadIdx.x;              // 192 threads
    const float4 v = ((const float4*)partials)[tid];
    double s = (double)v.x + (double)v.y + (double)v.z + (double)v.w;
    #pragma unroll
    for (int o = 32; o > 0; o >>= 1) s += __shfl_down(s, o, 64);
    __shared__ double r[3];
    if ((tid & 63) == 0) r[tid >> 6] = s;
    __syncthreads();
    if (tid == 0) out[0] = (float)((r[0] + r[1] + r[2]) / (double)N);
}

extern "C" void kernel_launch(void* const* d_in, const int* in_sizes, int n_in,
                              void* d_out, int out_size, void* d_ws, size_t ws_size,
                              hipStream_t stream) {
    const float* x1 = (const float*)d_in[0];
    const float* x2 = (const float*)d_in[1];

    char* ws = (char*)d_ws;
    const size_t MBYTES = (size_t)N * D;                  // 2 MiB per fp8 matrix
    unsigned* x1q = (unsigned*)(ws);
    unsigned* x2q = (unsigned*)(ws + MBYTES);
    unsigned* pq  = (unsigned*)(ws + 2 * MBYTES);
    float* sq1 = (float*)(ws + 3 * MBYTES);
    float* sq2 = (float*)(ws + 3 * MBYTES + (size_t)N * 4);
    float* sqp = (float*)(ws + 3 * MBYTES + (size_t)N * 8);
    float* partials = (float*)(ws + 3 * MBYTES + (size_t)N * 12);

    prep_kernel<<<N / 4, 256, 0, stream>>>(x1, x2, x1q, x2q, pq, sq1, sq2, sqp);
    mqjs_main<<<NBLOCK, 1024, 0, stream>>>(
        (const unsigned char*)x1q, (const unsigned char*)x2q, (const unsigned char*)pq,
        sq1, sq2, sqp, partials);
    finalize_kernel<<<1, 192, 0, stream>>>(partials, (float*)d_out);
}

// Round 15
// 171.637 us; speedup vs baseline: 1.7303x; 1.7303x over previous
//
#include <hip/hip_runtime.h>

#define N 8192
#define D 256
#define BM 128                    // I-tile rows (per task)
#define BJ 64                     // J-tile rows (per jj step)
#define JG 8                      // J-tiles per task
#define GJ (N / BJ / JG)          // 16
#define GI (N / BM)               // 64
#define NBLOCK (GI * GJ)          // 1024 blocks; wave w handles slice owv=w for all 3 z

typedef int   i32x8 __attribute__((ext_vector_type(8)));
typedef float f32x4 __attribute__((ext_vector_type(4)));
typedef float f32x2 __attribute__((ext_vector_type(2)));

// -------- prep: fp32 -> fp8 e4m3 (packed), norms of the DEQUANTIZED values ----
__device__ __forceinline__ unsigned pack_fp8x4(float a, float b, float c, float d) {
    unsigned lo = __builtin_amdgcn_cvt_pk_fp8_f32(a, b, 0, false);
    return __builtin_amdgcn_cvt_pk_fp8_f32(c, d, lo, true);
}
__device__ __forceinline__ float dequant_sumsq(unsigned q) {
    const float v0 = __builtin_amdgcn_cvt_f32_fp8(q, 0);
    const float v1 = __builtin_amdgcn_cvt_f32_fp8(q, 1);
    const float v2 = __builtin_amdgcn_cvt_f32_fp8(q, 2);
    const float v3 = __builtin_amdgcn_cvt_f32_fp8(q, 3);
    return fmaf(v0, v0, fmaf(v1, v1, fmaf(v2, v2, v3 * v3)));
}

__global__ void prep_kernel(const float* __restrict__ x1, const float* __restrict__ x2,
                            unsigned* __restrict__ x1q, unsigned* __restrict__ x2q,
                            unsigned* __restrict__ pq,
                            float* __restrict__ sq1, float* __restrict__ sq2,
                            float* __restrict__ sqp) {
    const int tid = threadIdx.x, lane = tid & 63, wv = tid >> 6;
    const int row = blockIdx.x * 4 + wv;
    const size_t eb = (size_t)row * D + lane * 4;
    const float4 a = *(const float4*)(x1 + eb);
    const float4 b = *(const float4*)(x2 + eb);
    const float px = 0.5f * (a.x + b.x), py = 0.5f * (a.y + b.y);
    const float pz = 0.5f * (a.z + b.z), pw = 0.5f * (a.w + b.w);
    const unsigned qa = pack_fp8x4(a.x, a.y, a.z, a.w);
    const unsigned qb = pack_fp8x4(b.x, b.y, b.z, b.w);
    const unsigned qp = pack_fp8x4(px, py, pz, pw);
    const size_t wb = (size_t)row * (D / 4) + lane;
    x1q[wb] = qa; x2q[wb] = qb; pq[wb] = qp;
    float s1 = dequant_sumsq(qa), s2 = dequant_sumsq(qb), sp = dequant_sumsq(qp);
    #pragma unroll
    for (int o = 32; o > 0; o >>= 1) {
        s1 += __shfl_down(s1, o, 64);
        s2 += __shfl_down(s2, o, 64);
        sp += __shfl_down(sp, o, 64);
    }
    if (lane == 0) { sq1[row] = s1; sq2[row] = s2; sqp[row] = sp; }
}

// -------- main ---------------------------------------------------------------
__device__ __forceinline__ f32x4 mfma8(i32x8 a, i32x8 b, f32x4 c) {
    return __builtin_amdgcn_mfma_scale_f32_16x16x128_f8f6f4(
        a, b, c, 0, 0, 0, 0x7F7F7F7F, 0, 0x7F7F7F7F);
}

__device__ __forceinline__ float logsumP(const f32x4 (&acc)[4][2],
                                         const f32x2 (&sa01)[4], const f32x2 (&sa23)[4],
                                         const float sb[2]) {
    float s = 0.0f;
    #pragma unroll
    for (int ti = 0; ti < 4; ++ti) {
        f32x2 pr = {1.0f, 1.0f};
        #pragma unroll
        for (int tj = 0; tj < 2; ++tj) {
            const f32x2 sbv = {sb[tj], sb[tj]};
            const f32x2 t01 = sa01[ti] + sbv, t23 = sa23[ti] + sbv;
            const f32x2 v01 = {acc[ti][tj][0], acc[ti][tj][1]};
            const f32x2 v23 = {acc[ti][tj][2], acc[ti][tj][3]};
            f32x2 d01 = t01 - 2.0f * v01;
            f32x2 d23 = t23 - 2.0f * v23;
            d01 = __builtin_elementwise_max(d01, (f32x2){1.0f, 1.0f});
            d23 = __builtin_elementwise_max(d23, (f32x2){1.0f, 1.0f});
            pr *= d01; pr *= d23;
        }
        s += __logf(pr.x * pr.y);   // product of 8 dists <= (1.5e3)^8, fp32-safe
    }
    return s;
}

__device__ __forceinline__ float logsumStraddle(const f32x4 (&acc)[4][2],
                                                const f32x2 (&sa01)[4], const f32x2 (&sa23)[4],
                                                const float sb[2],
                                                int wr, int wc, int quad, int l15,
                                                int I0, int J0) {
    float s = 0.0f;
    #pragma unroll
    for (int ti = 0; ti < 4; ++ti) {
        #pragma unroll
        for (int tj = 0; tj < 2; ++tj) {
            const int j = J0 + wc * 32 + tj * 16 + l15;
            float pr = 1.0f;
            #pragma unroll
            for (int r = 0; r < 4; ++r) {
                const int i = I0 + wr * 64 + ti * 16 + quad * 4 + r;
                const float sav = (r < 2) ? ((r & 1) ? sa01[ti].y : sa01[ti].x)
                                          : ((r & 1) ? sa23[ti].y : sa23[ti].x);
                float d = fmaf(-2.0f, acc[ti][tj][r], sav + sb[tj]);
                d = fmaxf(d, 1.0f);
                const float t = (j > i) ? d : 1.0f;
                const float u = (j >= i) ? d : 1.0f;
                pr *= t * u;
            }
            s += __logf(pr);
        }
    }
    return s;
}

// 256 threads = 4 independent wave-streams; each wave runs its 64x32 slice for
// all three products (z=0: x1.p, z=1: x2.p, z=2: x1.x1 upper). No loop barriers.
__global__ __launch_bounds__(256) void mqjs_main(
    const unsigned char* __restrict__ x1q, const unsigned char* __restrict__ x2q,
    const unsigned char* __restrict__ pq,
    const float* __restrict__ sq1, const float* __restrict__ sq2,
    const float* __restrict__ sqp, float* __restrict__ partials) {

    __shared__ float red[4];

    const int tid = threadIdx.x;
    const int lane = tid & 63;
    const int wv = tid >> 6;
    const int wr = wv >> 1, wc = wv & 1;      // wave slice: 64 I-rows x 32 J-cols
    const int quad = lane >> 4, l15 = lane & 15;

    const int by = blockIdx.x / GJ, bx = blockIdx.x - by * GJ;
    const int I0 = by * BM;
    const int jbase = bx * JG;
    const float wse = -(float)N / (float)(N - 1);

    float tsum = 0.0f;

    for (int z = 0; z < 3; ++z) {
        int jj0 = 0;
        if (z == 2) {
            jj0 = 2 * by - jbase;
            if (jj0 < 0) jj0 = 0;
            if (jj0 >= JG) break;
        }
        const unsigned char* Ag = (z == 1) ? x2q : x1q;
        const unsigned char* Bg = (z == 2) ? x1q : pq;
        const float* sqAg = (z == 1) ? sq2 : sq1;
        const float* sqBg = (z == 2) ? sq1 : sqp;
        const float wz = (z < 2) ? 0.5f : 0.0f;   // z==2 handled below

        // A fragments + sqA from global (L2-hot; 3x per block total)
        i32x8 af[2][4];
        f32x2 sa01[4], sa23[4];
        #pragma unroll
        for (int ti = 0; ti < 4; ++ti) {
            #pragma unroll
            for (int kc = 0; kc < 2; ++kc) {
                const size_t ro = (size_t)(I0 + wr * 64 + ti * 16 + l15) * D + kc * 128 + quad * 32;
                af[kc][ti] = *(const i32x8*)(Ag + ro);
            }
            const int sbase = I0 + wr * 64 + ti * 16 + quad * 4;
            sa01[ti] = (f32x2){sqAg[sbase], sqAg[sbase + 1]};
            sa23[ti] = (f32x2){sqAg[sbase + 2], sqAg[sbase + 3]};
        }

        for (int jj = jj0; jj < JG; ++jj) {
            const int J0 = (jbase + jj) * BJ;

            i32x8 bfr[2][2];                   // direct global loads (L2/LLC-hot)
            #pragma unroll
            for (int kc = 0; kc < 2; ++kc)
                #pragma unroll
                for (int tj = 0; tj < 2; ++tj)
                    bfr[kc][tj] = *(const i32x8*)(Bg +
                        (size_t)(J0 + wc * 32 + tj * 16 + l15) * D + kc * 128 + quad * 32);

            float sb[2];
            #pragma unroll
            for (int tj = 0; tj < 2; ++tj) sb[tj] = sqBg[J0 + wc * 32 + tj * 16 + l15];

            f32x4 acc[4][2];
            #pragma unroll
            for (int a = 0; a < 4; ++a)
                #pragma unroll
                for (int b = 0; b < 2; ++b)
                    acc[a][b] = (f32x4){0.f, 0.f, 0.f, 0.f};
            #pragma unroll
            for (int kc = 0; kc < 2; ++kc)
                #pragma unroll
                for (int ti = 0; ti < 4; ++ti)
                    #pragma unroll
                    for (int tj = 0; tj < 2; ++tj)
                        acc[ti][tj] = mfma8(af[kc][ti], bfr[kc][tj], acc[ti][tj]);

            if (z < 2) {
                tsum += wz * logsumP(acc, sa01, sa23, sb);
            } else if (J0 >= I0 + BM) {
                tsum += wse * logsumP(acc, sa01, sa23, sb);      // upper full: 2 * 0.5 * wse
            } else {
                tsum += 0.5f * wse * logsumStraddle(acc, sa01, sa23, sb, wr, wc, quad, l15, I0, J0);
            }
        }
    }

    #pragma unroll
    for (int o = 32; o > 0; o >>= 1) tsum += __shfl_down(tsum, o, 64);
    if (lane == 0) red[wv] = tsum;
    __syncthreads();
    if (tid == 0) partials[blockIdx.x] = red[0] + red[1] + red[2] + red[3];
}

// reduce 1024 partials (double accumulation) -> final scalar
__global__ void finalize_kernel(const float* __restrict__ partials, float* __restrict__ out) {
    const int tid = threadIdx.x;              // 256 threads
    const float4 v = ((const float4*)partials)[tid];
    double s = (double)v.x + (double)v.y + (double)v.z + (double)v.w;
    #pragma unroll
    for (int o = 32; o > 0; o >>= 1) s += __shfl_down(s, o, 64);
    __shared__ double r[4];
    if ((tid & 63) == 0) r[tid >> 6] = s;
    __syncthreads();
    if (tid == 0) out[0] = (float)((r[0] + r[1] + r[2] + r[3]) / (double)N);
}

extern "C" void kernel_launch(void* const* d_in, const int* in_sizes, int n_in,
                              void* d_out, int out_size, void* d_ws, size_t ws_size,
                              hipStream_t stream) {
    const float* x1 = (const float*)d_in[0];
    const float* x2 = (const float*)d_in[1];

    char* ws = (char*)d_ws;
    const size_t MBYTES = (size_t)N * D;                  // 2 MiB per fp8 matrix
    unsigned* x1q = (unsigned*)(ws);
    unsigned* x2q = (unsigned*)(ws + MBYTES);
    unsigned* pq  = (unsigned*)(ws + 2 * MBYTES);
    float* sq1 = (float*)(ws + 3 * MBYTES);
    float* sq2 = (float*)(ws + 3 * MBYTES + (size_t)N * 4);
    float* sqp = (float*)(ws + 3 * MBYTES + (size_t)N * 8);
    float* partials = (float*)(ws + 3 * MBYTES + (size_t)N * 12);

    prep_kernel<<<N / 4, 256, 0, stream>>>(x1, x2, x1q, x2q, pq, sq1, sq2, sqp);
    mqjs_main<<<NBLOCK, 256, 0, stream>>>(
        (const unsigned char*)x1q, (const unsigned char*)x2q, (const unsigned char*)pq,
        sq1, sq2, sqp, partials);
    finalize_kernel<<<1, 256, 0, stream>>>(partials, (float*)d_out);
}